// Round 6
// baseline (3607.712 us; speedup 1.0000x reference)
//
#include <hip/hip_runtime.h>
#include <cmath>

// PhaseAwareClassifier on MI355X — R6: split-bf16 MFMA.
// v_pk_fma_f32 is half-rate (fp32 peak 157.3 TF scalar-equiv) -> VALU floor
// ~1.14 ms. Break it with bf16 MFMA (2.5 PF) + hi/lo fp32 emulation:
//   x = hi(bf16) + lo(bf16);  C*O ~= Chi*Ohi + Chi*Olo + Clo*Ohi  (fp32 acc)
// Per block: G[160,64] = C[160,160] * O[160,64] complex; 16x16x32 MFMA;
// 8 waves x (5 M-tiles x 1 N-tile), acc holds 4*field persistently.
// O state in LDS as 4 bf16 matrices [n=64][k=160] (80 KB, 2 blocks/CU).

#define NSTEPS  10
#define INJ_ST  4

typedef __bf16 bf16x8 __attribute__((ext_vector_type(8)));
typedef __bf16 bf16x4 __attribute__((ext_vector_type(4)));
typedef short  short8 __attribute__((ext_vector_type(8)));
typedef float  f32x4  __attribute__((ext_vector_type(4)));

// workspace layout (float offsets)
#define WS_MAX    0          // 1      enc_max (uint-ordered float)
#define WS_ENERGY 64         // 1280   energy[b][10]
#define WS_GSP    2048       // 160    softplus(gain), zero-padded
#define WS_CONN   4096       // 4 bf16 matrices [160][160]: Crh,Crl,Cih,Cil
                             //   = 4*25600 ushorts = 51200 floats
#define WS_INJ    55296      // 100352 inj[b][49][16] = px * 1.02/enc_max (=3.4*0.3)

__global__ void k_init(float* ws) {
    int i = blockIdx.x * 256 + threadIdx.x;
    if (i == 0) ws[WS_MAX] = 0.f;
    if (i < 1280) ws[WS_ENERGY + i] = 0.f;
}

__global__ void k_max(const float* __restrict__ img, float* ws, int n) {
    __shared__ float sm[256];
    float v = 0.f;
    for (int i = blockIdx.x * blockDim.x + threadIdx.x; i < n; i += gridDim.x * blockDim.x)
        v = fmaxf(v, fabsf(img[i]));
    sm[threadIdx.x] = v;
    __syncthreads();
    for (int s = 128; s > 0; s >>= 1) {
        if (threadIdx.x < s) sm[threadIdx.x] = fmaxf(sm[threadIdx.x], sm[threadIdx.x + s]);
        __syncthreads();
    }
    if (threadIdx.x == 0)
        atomicMax((unsigned int*)(ws + WS_MAX), __float_as_uint(sm[0]));
}

__global__ void k_prep(const float* __restrict__ img,
                       const float* __restrict__ cr, const float* __restrict__ ci,
                       const float* __restrict__ phase, const float* __restrict__ gain,
                       float* ws) {
    int i = blockIdx.x * 256 + threadIdx.x;
    __bf16* Cb = (__bf16*)(ws + WS_CONN);
    if (i < 25600) {                       // conn: A[m=j][k=s], 160x160
        int jj = i / 160, ss = i % 160;
        float vr = 0.f, vi = 0.f;
        if (jj < 131 && ss < 131) {
            float a = cr[ss * 131 + jj], b = ci[ss * 131 + jj];
            float ph = phase[jj];
            float cp = cosf(ph), sp = sinf(ph);
            vr = a * cp - b * sp;
            vi = a * sp + b * cp;
        }
        __bf16 rh = (__bf16)vr;  __bf16 rl = (__bf16)(vr - (float)rh);
        __bf16 ih = (__bf16)vi;  __bf16 il = (__bf16)(vi - (float)ih);
        Cb[i] = rh; Cb[25600 + i] = rl; Cb[51200 + i] = ih; Cb[76800 + i] = il;
    } else if (i < 25760) {
        int j = i - 25600;
        float g = 0.f;
        if (j < 131) {
            float x = gain[j];
            g = (x > 20.f) ? x : log1pf(expf(x));  // softplus
        }
        ws[WS_GSP + j] = g;                 // zero for padded rows -> out=0
    } else if (i < 25760 + 128 * 49 * 16) {
        int q = i - 25760;
        int m = q & 15, jj = (q >> 4) % 49, b = q / (49 * 16);
        int u = m >> 2, v2 = m & 3, pi = jj / 7, pj = jj % 7;
        float px = img[b * 784 + (pi * 4 + u) * 28 + (pj * 4 + v2)];
        float mx = ws[WS_MAX];
        float sc = (mx > 1e-8f) ? (1.02f / mx) : 1.02f;   // 3.4 * 0.3
        ws[WS_INJ + q] = px * sc;
    }
}

static __device__ __forceinline__ f32x4 MF(bf16x8 a, bf16x8 b, f32x4 c) {
    return __builtin_amdgcn_mfma_f32_16x16x32_bf16(a, b, c, 0, 0, 0);
}
static __device__ __forceinline__ bf16x8 bneg(bf16x8 a) {
    short8 t = __builtin_bit_cast(short8, a) ^ (short8)(short)0x8000;
    return __builtin_bit_cast(bf16x8, t);
}

__global__ __launch_bounds__(512, 4)
void k_main(const float* __restrict__ ws, float* __restrict__ energy) {
    // O state: 4 bf16 matrices [n=64][k=160] (rh, rl, ih, il)
    __shared__ __bf16 OB[4][64 * 160];             // 81,920 B -> 2 blocks/CU
    const int tid  = threadIdx.x;
    const int lane = tid & 63;
    const int ln15 = lane & 15;
    const int quad = lane >> 4;
    const int wv   = __builtin_amdgcn_readfirstlane(tid >> 6);  // 0..7
    const int ntile = wv & 3;
    const int mhalf = wv >> 2;
    const int nidx  = ntile * 16 + ln15;            // this lane's column 0..63
    const int c = blockIdx.x * 64 + nidx;
    const int b = c >> 10;
    const int l = (c >> 4) & 63;
    const int m = c & 15;
    const float wl = 1.0f - fabsf((float)l - 32.0f) * (1.0f / 64.0f);

    const __bf16* __restrict__ Cb  = (const __bf16*)(ws + WS_CONN);
    const __bf16* __restrict__ Crh = Cb;
    const __bf16* __restrict__ Crl = Cb + 25600;
    const __bf16* __restrict__ Cih = Cb + 51200;
    const __bf16* __restrict__ Cil = Cb + 76800;
    const float* __restrict__ gsp  = ws + WS_GSP;
    const float* __restrict__ injb = ws + WS_INJ;

    __bf16* __restrict__ OBrh = &OB[0][0];
    __bf16* __restrict__ OBrl = &OB[1][0];
    __bf16* __restrict__ OBih = &OB[2][0];
    __bf16* __restrict__ OBil = &OB[3][0];

    f32x4 accr[5], acci[5];                         // acc == 4 * field
#pragma unroll
    for (int p = 0; p < 5; ++p) { accr[p] = (f32x4)0.f; acci[p] = (f32x4)0.f; }

    // zero O state
    {
        int* obi = (int*)&OB[0][0];
        for (int i = tid; i < 20480; i += 512) obi[i] = 0;
    }

    // injection add (field += inj  =>  acc += 3.4*inj_raw*wl), real part only
    auto inj_add = [&]() {
        if (mhalf == 0) {
#pragma unroll
            for (int p = 0; p < 4; ++p) {           // tiles 0..3 cover j<64
#pragma unroll
                for (int r = 0; r < 4; ++r) {
                    int j = p * 16 + quad * 4 + r;
                    if (j < 49) accr[p][r] += injb[(b * 49 + j) * 16 + m] * wl;
                }
            }
        }
    };

    // epilogue: out = tanh-rescale(0.25*acc), split hi/lo, write B-layout LDS
    auto epilogue = [&]() {
#pragma unroll
        for (int p = 0; p < 5; ++p) {
            const int j0 = (mhalf * 5 + p) * 16 + quad * 4;
            float g4[4];
            *(float4*)g4 = *(const float4*)(gsp + j0);
            bf16x4 prh, prl, pih, pil;
#pragma unroll
            for (int r = 0; r < 4; ++r) {
                float fr = accr[p][r] * 0.25f;
                float fi = acci[p][r] * 0.25f;
                float mag = sqrtf(fr * fr + fi * fi + 1e-8f);
                float y = mag * g4[r];
                float e = __expf(-2.0f * y);
                float th = 1.0f - 2.0f * e * __builtin_amdgcn_rcpf(1.0f + e);
                float scv = th * __builtin_amdgcn_rcpf(mag + 1e-8f);
                float orv = fr * scv, oiv = fi * scv;
                __bf16 h;
                h = (__bf16)orv; prh[r] = h; prl[r] = (__bf16)(orv - (float)h);
                h = (__bf16)oiv; pih[r] = h; pil[r] = (__bf16)(oiv - (float)h);
            }
            const int off = nidx * 160 + j0;        // k-contiguous quad
            *(bf16x4*)(OBrh + off) = prh;
            *(bf16x4*)(OBrl + off) = prl;
            *(bf16x4*)(OBih + off) = pih;
            *(bf16x4*)(OBil + off) = pil;
        }
    };

    __syncthreads();
    inj_add();                                      // t = 0 (g term is zero)
    epilogue();
    __syncthreads();

    for (int t = 1; t < NSTEPS; ++t) {
        // decay pre-scale + injection
#pragma unroll
        for (int p = 0; p < 5; ++p) { accr[p] *= 0.85f; acci[p] *= 0.85f; }
        if (t < INJ_ST) inj_add();

        // ---- MFMA phase: G += C * O (complex, split-bf16) ----
#pragma unroll
        for (int kt = 0; kt < 5; ++kt) {
            const int k0 = kt * 32 + quad * 8;
            const int boff = nidx * 160 + k0;
            bf16x8 b_rh = *(const bf16x8*)(OBrh + boff);
            bf16x8 b_rl = *(const bf16x8*)(OBrl + boff);
            bf16x8 b_ih = *(const bf16x8*)(OBih + boff);
            bf16x8 b_il = *(const bf16x8*)(OBil + boff);
            bf16x8 b_nih = bneg(b_ih);              // for G_r -= Ci*Oi
            bf16x8 b_nil = bneg(b_il);
#pragma unroll
            for (int p = 0; p < 5; ++p) {
                const int aoff = ((mhalf * 5 + p) * 16 + ln15) * 160 + k0;
                bf16x8 a_rh = *(const bf16x8*)(Crh + aoff);
                bf16x8 a_rl = *(const bf16x8*)(Crl + aoff);
                bf16x8 a_ih = *(const bf16x8*)(Cih + aoff);
                bf16x8 a_il = *(const bf16x8*)(Cil + aoff);
                f32x4 ar = accr[p], ai = acci[p];
                // G_r += Cr*Or
                ar = MF(a_rh, b_rh, ar); ar = MF(a_rh, b_rl, ar); ar = MF(a_rl, b_rh, ar);
                // G_r -= Ci*Oi   (negated Oi fragments)
                ar = MF(a_ih, b_nih, ar); ar = MF(a_ih, b_nil, ar); ar = MF(a_il, b_nih, ar);
                // G_i += Cr*Oi
                ai = MF(a_rh, b_ih, ai); ai = MF(a_rh, b_il, ai); ai = MF(a_rl, b_ih, ai);
                // G_i += Ci*Or
                ai = MF(a_ih, b_rh, ai); ai = MF(a_ih, b_rl, ai); ai = MF(a_il, b_rh, ai);
                accr[p] = ar; acci[p] = ai;
            }
        }
        __syncthreads();   // all reads of OB done
        epilogue();
        __syncthreads();   // OB ready for next step
    }

    // ---- energy: j = 121..130, sum over this block's 64 cols ----
    float v0 = 0.f, v1 = 0.f;
    {
        int e0 = tid >> 6, c0 = tid & 63, j = 121 + e0;
        int o = c0 * 160 + j;
        float orv = (float)OBrh[o] + (float)OBrl[o];
        float oiv = (float)OBih[o] + (float)OBil[o];
        v0 = orv * orv + oiv * oiv;
        if (tid < 128) {
            int i1 = tid + 512;
            int e1 = i1 >> 6, c1 = i1 & 63; j = 121 + e1;
            o = c1 * 160 + j;
            orv = (float)OBrh[o] + (float)OBrl[o];
            oiv = (float)OBih[o] + (float)OBil[o];
            v1 = orv * orv + oiv * oiv;
        }
    }
    __syncthreads();
    float* scr = (float*)&OB[0][0];
    scr[tid] = v0;
    if (tid < 128) scr[tid + 512] = v1;
    __syncthreads();
    if (tid < 10) {
        float ssum = 0.f;
        for (int cc = 0; cc < 64; ++cc) ssum += scr[tid * 64 + cc];
        atomicAdd(energy + ((blockIdx.x >> 4) * 10) + tid, ssum);
    }
}

__global__ void k_readout(const float* __restrict__ ws,
                          const float* __restrict__ W,
                          const float* __restrict__ bias,
                          float* __restrict__ out) {
    int i = blockIdx.x * 256 + threadIdx.x;
    if (i < 1280) {
        int b = i / 10, o = i % 10;
        float s = bias[o];
#pragma unroll
        for (int f = 0; f < 10; ++f) {
            float feat = log1pf(ws[WS_ENERGY + b * 10 + f] + 1e-8f);
            s = fmaf(feat, W[o * 10 + f], s);
        }
        out[i] = s;
    }
}

extern "C" void kernel_launch(void* const* d_in, const int* in_sizes, int n_in,
                              void* d_out, int out_size, void* d_ws, size_t ws_size,
                              hipStream_t stream) {
    const float* images = (const float*)d_in[0];
    const float* conn_r = (const float*)d_in[1];
    const float* conn_i = (const float*)d_in[2];
    const float* phase  = (const float*)d_in[3];
    const float* gain   = (const float*)d_in[4];
    const float* W      = (const float*)d_in[5];
    const float* bias   = (const float*)d_in[6];
    float* ws  = (float*)d_ws;
    float* out = (float*)d_out;

    hipLaunchKernelGGL(k_init, dim3(6), dim3(256), 0, stream, ws);
    hipLaunchKernelGGL(k_max, dim3(98), dim3(256), 0, stream, images, ws, 128 * 28 * 28);
    hipLaunchKernelGGL(k_prep, dim3(493), dim3(256), 0, stream,
                       images, conn_r, conn_i, phase, gain, ws);
    hipLaunchKernelGGL(k_main, dim3(2048), dim3(512), 0, stream, ws, ws + WS_ENERGY);
    hipLaunchKernelGGL(k_readout, dim3(5), dim3(256), 0, stream, ws, W, bias, out);
}